// Round 6
// baseline (1538.568 us; speedup 1.0000x reference)
//
#include <hip/hip_runtime.h>
#include <hip/hip_bf16.h>
#include <stdint.h>

typedef __bf16 bf16_t;
typedef __bf16 bf16x4 __attribute__((ext_vector_type(4)));
typedef __bf16 bf16x8 __attribute__((ext_vector_type(8)));
typedef float f32x4 __attribute__((ext_vector_type(4)));

static_assert(sizeof(bf16x8) == 16, "bf16x8 must be 16B");

#define MFMA_BF16(a, b, c) __builtin_amdgcn_mfma_f32_16x16x32_bf16((a), (b), (c), 0, 0, 0)

typedef const __attribute__((address_space(1))) void* gas_ptr;
typedef __attribute__((address_space(3))) void* las_ptr;

__device__ __forceinline__ void gload_lds16(const void* g, void* l) {
  // async global->LDS, 16B per lane; LDS dest = wave-uniform base + lane*16
  __builtin_amdgcn_global_load_lds((gas_ptr)g, (las_ptr)l, 16, 0, 0);
}

#define NEG_BIG (-1.0e30f)

// ---------------------------------------------------------------------------
// fp32 -> bf16 convert (inputs are float32 per the reference; compute in bf16)
// ---------------------------------------------------------------------------
__global__ __launch_bounds__(256) void cvt_kernel(const float* __restrict__ src,
                                                  bf16_t* __restrict__ dst) {
  const int i = (blockIdx.x * 256 + threadIdx.x) * 4;
  const f32x4 v = *(const f32x4*)(src + i);
  bf16x4 o;
  o[0] = (bf16_t)v[0];
  o[1] = (bf16_t)v[1];
  o[2] = (bf16_t)v[2];
  o[3] = (bf16_t)v[3];
  *(bf16x4*)(dst + i) = o;
}

// ---------------------------------------------------------------------------
// GEMM:  D[m][n] = sum_k A[m][k] * Bw[n][k]   (A row-major [M,512], Bw [N,512])
// 128x128 tile, BK=32, 4 waves (2x2) each 64x64, m97 structure. LDS = 16 KB.
// MODE 0: qkv epilogue -> q / k row-major (bf16), v transposed to vT[b][d][t]
// MODE 1: final epilogue -> o_f as FP32 (the reference's output dtype!)
// ---------------------------------------------------------------------------
template <int MODE>
__global__ __launch_bounds__(256, 2) void gemm_bt_kernel(
    const bf16_t* __restrict__ A, const bf16_t* __restrict__ Bw,
    bf16_t* __restrict__ o_q, bf16_t* __restrict__ o_k, bf16_t* __restrict__ o_vT,
    float* __restrict__ o_f) {
  constexpr int K = 512;
  __shared__ bf16_t As[128 * 32];
  __shared__ bf16_t Bs[128 * 32];

  const int tid = threadIdx.x;
  const int lane = tid & 63;
  const int wid = tid >> 6;
  const int quad = lane >> 4;
  const int l15 = lane & 15;
  const int wm = wid >> 1;
  const int wn = wid & 1;

  const int mt = blockIdx.x & 127;  // M = 16384 -> 128 m-tiles
  const int nt = blockIdx.x >> 7;
  const int row0 = mt * 128;
  const int col0 = nt * 128;

  f32x4 acc[4][4] = {};

  for (int kt = 0; kt < K; kt += 32) {
    __syncthreads();  // previous iter's reads done before restage
#pragma unroll
    for (int rnd = 0; rnd < 2; rnd++) {
      const int e = (rnd * 256 + tid) * 8;  // flat element in 128x32 tile
      const int r = e >> 5;
      const int c = e & 31;
      gload_lds16(A + (size_t)(row0 + r) * K + kt + c, As + e);
      gload_lds16(Bw + (size_t)(col0 + r) * K + kt + c, Bs + e);
    }
    __syncthreads();

    bf16x8 af[4], bfr[4];
#pragma unroll
    for (int i = 0; i < 4; i++)
      af[i] = *(const bf16x8*)(As + (wm * 64 + i * 16 + l15) * 32 + quad * 8);
#pragma unroll
    for (int i = 0; i < 4; i++)
      bfr[i] = *(const bf16x8*)(Bs + (wn * 64 + i * 16 + l15) * 32 + quad * 8);
#pragma unroll
    for (int mi = 0; mi < 4; mi++)
#pragma unroll
      for (int ni = 0; ni < 4; ni++)
        acc[mi][ni] = MFMA_BF16(af[mi], bfr[ni], acc[mi][ni]);
  }

  // epilogue: D row = quad*4+reg, col = l15 within each 16x16 subtile
#pragma unroll
  for (int mi = 0; mi < 4; mi++) {
    const int row = row0 + wm * 64 + mi * 16 + quad * 4;
#pragma unroll
    for (int ni = 0; ni < 4; ni++) {
      const int col = col0 + wn * 64 + ni * 16 + l15;
#pragma unroll
      for (int r = 0; r < 4; r++) {
        const int rr = row + r;
        if constexpr (MODE == 0) {
          const bf16_t bv = (bf16_t)acc[mi][ni][r];
          if (col < 512) {
            o_q[(size_t)rr * 512 + col] = bv;
          } else if (col < 1024) {
            o_k[(size_t)rr * 512 + (col - 512)] = bv;
          } else {
            const int bb = rr >> 12;
            const int t = rr & 4095;
            o_vT[((size_t)bb * 512 + (col - 1024)) * 4096 + t] = bv;
          }
        } else {
          o_f[(size_t)rr * 512 + col] = acc[mi][ni][r];  // fp32 output
        }
      }
    }
  }
}

// ---------------------------------------------------------------------------
// Flash attention, no head split (head dim = 512 = d_model). No LDS staging,
// no barriers: K and V MFMA B-fragments read DIRECTLY from global (both are
// 16B-contiguous per lane: K row-major gives k[row][kk*32+quad*8..+7]; vT
// gives vT[d][j*32+quad*8..+7]). Only LDS use is the m120-verified
// wave-private 16x32 P transpose (4 KB total). Waves fully autonomous:
// wave loops only j=0..jcomp. Inf-free online softmax. Output in-place over
// q (own rows only; q frags preloaded first).
// ---------------------------------------------------------------------------
__global__ __launch_bounds__(256, 1) void attn_kernel(
    const bf16_t* q, const bf16_t* __restrict__ k,
    const bf16_t* __restrict__ vT, bf16_t* o) {
  __shared__ bf16_t Ps[4 * 16 * 32];  // 4 KB, wave-private P scratch

  const int tid = threadIdx.x;
  const int lane = tid & 63;
  const int wid = tid >> 6;
  const int quad = lane >> 4;
  const int l15 = lane & 15;

  const int b = blockIdx.x >> 6;
  const int qt = blockIdx.x & 63;
  const int t0 = qt * 64 + wid * 16;  // this wave's q rows (within batch)

  const float scale = 0.044194173824159216f;  // 1/sqrt(512)

  // preload Q A-fragments: A[m=l15][k = kk*32 + quad*8 + j]
  bf16x8 qf[16];
  {
    const bf16_t* qp = q + ((size_t)(b * 4096 + t0 + l15)) * 512 + quad * 8;
#pragma unroll
    for (int kk = 0; kk < 16; kk++) qf[kk] = *(const bf16x8*)(qp + kk * 32);
  }

  f32x4 oacc[32] = {};  // O[16 x 512] C-layout: oacc[n][r] = O[quad*4+r][n*16+l15]
  float mrow[4], lrow[4];
#pragma unroll
  for (int r = 0; r < 4; r++) {
    mrow[r] = NEG_BIG;
    lrow[r] = 0.0f;
  }

  const int jcomp = (t0 + 15) >> 5;  // last KV tile with any visible col
  const bf16_t* kbase = k + (size_t)b * 4096 * 512;
  const bf16_t* vbase = vT + (size_t)b * 512 * 4096;

  for (int j = 0; j <= jcomp; j++) {
    // ---- S[16x32] = Q . K^T ; B-frag kf = K[n=l15 (+16)][kk*32+quad*8..+7]
    f32x4 s0 = {}, s1 = {};
    const bf16_t* krow0 = kbase + (size_t)(j * 32 + l15) * 512 + quad * 8;
    const bf16_t* krow1 = krow0 + 16 * 512;
#pragma unroll
    for (int kk = 0; kk < 16; kk++) {
      const bf16x8 kf0 = *(const bf16x8*)(krow0 + kk * 32);
      const bf16x8 kf1 = *(const bf16x8*)(krow1 + kk * 32);
      s0 = MFMA_BF16(qf[kk], kf0, s0);
      s1 = MFMA_BF16(qf[kk], kf1, s1);
    }

    // ---- scale + causal mask + inf-free online softmax
    float p0[4], p1[4], alpha[4];
#pragma unroll
    for (int r = 0; r < 4; r++) {
      const int trow = t0 + quad * 4 + r;
      const int c0 = j * 32 + l15;
      const float v0 = (c0 <= trow) ? s0[r] * scale : NEG_BIG;
      const float v1 = (c0 + 16 <= trow) ? s1[r] * scale : NEG_BIG;
      float mx = fmaxf(v0, v1);
      mx = fmaxf(mx, __shfl_xor(mx, 1));
      mx = fmaxf(mx, __shfl_xor(mx, 2));
      mx = fmaxf(mx, __shfl_xor(mx, 4));
      mx = fmaxf(mx, __shfl_xor(mx, 8));
      if (mx > 0.5f * NEG_BIG) {  // row has >=1 visible column in this tile
        const float mnew = fmaxf(mrow[r], mx);
        alpha[r] = __expf(mrow[r] - mnew);  // finite-finite -> no NaN
        const float e0 = __expf(v0 - mnew);
        const float e1 = __expf(v1 - mnew);
        float rs = e0 + e1;
        rs += __shfl_xor(rs, 1);
        rs += __shfl_xor(rs, 2);
        rs += __shfl_xor(rs, 4);
        rs += __shfl_xor(rs, 8);
        lrow[r] = lrow[r] * alpha[r] + rs;
        mrow[r] = mnew;
        p0[r] = e0;
        p1[r] = e1;
      } else {  // fully masked row-tile: exact no-op
        alpha[r] = 1.0f;
        p0[r] = 0.0f;
        p1[r] = 0.0f;
      }
    }
#pragma unroll
    for (int n = 0; n < 32; n++) {
#pragma unroll
      for (int r = 0; r < 4; r++) oacc[n][r] *= alpha[r];
    }

    // ---- P: C-layout -> A-layout via wave-private LDS (m120-verified)
    bf16_t* Pw = Ps + wid * 512;
#pragma unroll
    for (int r = 0; r < 4; r++) {
      Pw[(quad * 4 + r) * 32 + l15] = (bf16_t)p0[r];
      Pw[(quad * 4 + r) * 32 + 16 + l15] = (bf16_t)p1[r];
    }
    const bf16x8 pf = *(const bf16x8*)(Pw + l15 * 32 + quad * 8);

    // ---- O += P . V ; B-frag vf = V[c=quad*8..+7][d=n*16+l15] from vT
    const bf16_t* vcol = vbase + (size_t)l15 * 4096 + j * 32 + quad * 8;
#pragma unroll
    for (int n = 0; n < 32; n++) {
      const bf16x8 vf = *(const bf16x8*)(vcol + (size_t)n * 16 * 4096);
      oacc[n] = MFMA_BF16(pf, vf, oacc[n]);
    }
  }

  // ---- epilogue: O / l -> bf16, in-place over this wave's own q rows
#pragma unroll
  for (int r = 0; r < 4; r++) {
    const float inv = 1.0f / lrow[r];
    bf16_t* orow = o + ((size_t)(b * 4096 + t0 + quad * 4 + r)) * 512;
#pragma unroll
    for (int n = 0; n < 32; n++) orow[n * 16 + l15] = (bf16_t)(oacc[n][r] * inv);
  }
}

// ---------------------------------------------------------------------------
extern "C" void kernel_launch(void* const* d_in, const int* in_sizes, int n_in,
                              void* d_out, int out_size, void* d_ws, size_t ws_size,
                              hipStream_t stream) {
  const float* x_f = (const float*)d_in[0];   // [4,4096,512] fp32
  const float* wq_f = (const float*)d_in[1];  // [1536,512]   fp32
  const float* wp_f = (const float*)d_in[2];  // [512,512]    fp32
  float* out = (float*)d_out;                 // [4,4096,512] FP32 (ref output dtype)

  // workspace layout (bf16 elements):
  //   xb (16MB) | wqb (1.5MB) | wpb (0.5MB) | q (16MB) | k (16MB) | vT (16MB)
  bf16_t* xb = (bf16_t*)d_ws;
  bf16_t* wqb = xb + (size_t)16384 * 512;
  bf16_t* wpb = wqb + (size_t)1536 * 512;
  bf16_t* q = wpb + (size_t)512 * 512;
  bf16_t* kk = q + (size_t)16384 * 512;
  bf16_t* vT = kk + (size_t)16384 * 512;

  // 0) convert fp32 inputs -> bf16
  cvt_kernel<<<(16384 * 512) / 1024, 256, 0, stream>>>(x_f, xb);
  cvt_kernel<<<(1536 * 512) / 1024, 256, 0, stream>>>(wq_f, wqb);
  cvt_kernel<<<(512 * 512) / 1024, 256, 0, stream>>>(wp_f, wpb);

  // 1) qkv = x @ Wqkv^T ; v stored transposed
  gemm_bt_kernel<0><<<128 * 12, 256, 0, stream>>>(xb, wqb, q, kk, vT, nullptr);
  // 2) causal attention (output overwrites q in place)
  attn_kernel<<<256, 256, 0, stream>>>(q, kk, vT, q);
  // 3) y = attn @ Wproj^T -> fp32 d_out
  gemm_bt_kernel<1><<<128 * 4, 256, 0, stream>>>(q, wpb, nullptr, nullptr, nullptr, out);
}

// Round 7
// 998.140 us; speedup vs baseline: 1.5414x; 1.5414x over previous
//
#include <hip/hip_runtime.h>
#include <hip/hip_bf16.h>
#include <stdint.h>

typedef __bf16 bf16_t;
typedef __bf16 bf16x4 __attribute__((ext_vector_type(4)));
typedef __bf16 bf16x8 __attribute__((ext_vector_type(8)));
typedef float f32x4 __attribute__((ext_vector_type(4)));

static_assert(sizeof(bf16x8) == 16, "bf16x8 must be 16B");

#define MFMA_BF16(a, b, c) __builtin_amdgcn_mfma_f32_16x16x32_bf16((a), (b), (c), 0, 0, 0)

typedef const __attribute__((address_space(1))) void* gas_ptr;
typedef __attribute__((address_space(3))) void* las_ptr;

__device__ __forceinline__ void gload_lds16(const void* g, void* l) {
  __builtin_amdgcn_global_load_lds((gas_ptr)g, (las_ptr)l, 16, 0, 0);
}

#define NEG_BIG (-1.0e30f)

// ---------------------------------------------------------------------------
// fp32 -> bf16 convert
// ---------------------------------------------------------------------------
__global__ __launch_bounds__(256) void cvt_kernel(const float* __restrict__ src,
                                                  bf16_t* __restrict__ dst) {
  const int i = (blockIdx.x * 256 + threadIdx.x) * 4;
  const f32x4 v = *(const f32x4*)(src + i);
  bf16x4 o;
  o[0] = (bf16_t)v[0];
  o[1] = (bf16_t)v[1];
  o[2] = (bf16_t)v[2];
  o[3] = (bf16_t)v[3];
  *(bf16x4*)(dst + i) = o;
}

// ---------------------------------------------------------------------------
// GEMM (m97 structure): D[m][n] = sum_k A[m][k] * Bw[n][k]
// MODE 0: qkv epilogue -> q / k row-major (bf16), v transposed to vT[b][d][t]
// MODE 1: final epilogue -> o_f as FP32 (reference output dtype)
// ---------------------------------------------------------------------------
template <int MODE>
__global__ __launch_bounds__(256, 2) void gemm_bt_kernel(
    const bf16_t* __restrict__ A, const bf16_t* __restrict__ Bw,
    bf16_t* __restrict__ o_q, bf16_t* __restrict__ o_k, bf16_t* __restrict__ o_vT,
    float* __restrict__ o_f) {
  constexpr int K = 512;
  __shared__ bf16_t As[128 * 32];
  __shared__ bf16_t Bs[128 * 32];

  const int tid = threadIdx.x;
  const int lane = tid & 63;
  const int wid = tid >> 6;
  const int quad = lane >> 4;
  const int l15 = lane & 15;
  const int wm = wid >> 1;
  const int wn = wid & 1;

  const int mt = blockIdx.x & 127;
  const int nt = blockIdx.x >> 7;
  const int row0 = mt * 128;
  const int col0 = nt * 128;

  f32x4 acc[4][4] = {};

  for (int kt = 0; kt < K; kt += 32) {
    __syncthreads();
#pragma unroll
    for (int rnd = 0; rnd < 2; rnd++) {
      const int e = (rnd * 256 + tid) * 8;
      const int r = e >> 5;
      const int c = e & 31;
      gload_lds16(A + (size_t)(row0 + r) * K + kt + c, As + e);
      gload_lds16(Bw + (size_t)(col0 + r) * K + kt + c, Bs + e);
    }
    __syncthreads();

    bf16x8 af[4], bfr[4];
#pragma unroll
    for (int i = 0; i < 4; i++)
      af[i] = *(const bf16x8*)(As + (wm * 64 + i * 16 + l15) * 32 + quad * 8);
#pragma unroll
    for (int i = 0; i < 4; i++)
      bfr[i] = *(const bf16x8*)(Bs + (wn * 64 + i * 16 + l15) * 32 + quad * 8);
#pragma unroll
    for (int mi = 0; mi < 4; mi++)
#pragma unroll
      for (int ni = 0; ni < 4; ni++)
        acc[mi][ni] = MFMA_BF16(af[mi], bfr[ni], acc[mi][ni]);
  }

#pragma unroll
  for (int mi = 0; mi < 4; mi++) {
    const int row = row0 + wm * 64 + mi * 16 + quad * 4;
#pragma unroll
    for (int ni = 0; ni < 4; ni++) {
      const int col = col0 + wn * 64 + ni * 16 + l15;
#pragma unroll
      for (int r = 0; r < 4; r++) {
        const int rr = row + r;
        if constexpr (MODE == 0) {
          const bf16_t bv = (bf16_t)acc[mi][ni][r];
          if (col < 512) {
            o_q[(size_t)rr * 512 + col] = bv;
          } else if (col < 1024) {
            o_k[(size_t)rr * 512 + (col - 512)] = bv;
          } else {
            const int bb = rr >> 12;
            const int t = rr & 4095;
            o_vT[((size_t)bb * 512 + (col - 1024)) * 4096 + t] = bv;
          }
        } else {
          o_f[(size_t)rr * 512 + col] = acc[mi][ni][r];
        }
      }
    }
  }
}

// ---------------------------------------------------------------------------
// Flash attention, d-split for occupancy. Grid = 1024 strips x 2 d-halves =
// 2048 single-wave blocks (heavy strips dispatched first). Each wave:
//   - 16 q-rows (strip), FULL-D S-phase (duplicated across the 2 halves),
//   - half-D (256-col) PV + O-accumulator -> oacc 64 VGPR, total ~180 VGPR
//     => 2 waves/SIMD => 8 resident waves/CU at grid 2048 (vs 1.9 before).
// No barriers, no staging; only LDS = 0.5 KB wave-private P transpose.
// Output -> separate buffer (xb, dead after GEMM1): q stays read-only, so
// the two halves of a strip can't race on it.
// ---------------------------------------------------------------------------
__global__ __launch_bounds__(64, 2) void attn_kernel(
    const bf16_t* __restrict__ q, const bf16_t* __restrict__ k,
    const bf16_t* __restrict__ vT, bf16_t* __restrict__ o) {
  __shared__ bf16_t Ps[16 * 32];  // 1 KB, single-wave P scratch

  const int lane = threadIdx.x & 63;
  const int quad = lane >> 4;
  const int l15 = lane & 15;

  const int bid = blockIdx.x;      // 0..2047
  const int half = bid & 1;        // output-d half
  const int sidx = bid >> 1;       // 0..1023 strip slot
  const int b = sidx & 3;          // batch
  const int t = 255 - (sidx >> 2); // heavy-first: large t dispatched first
  const int t0 = t * 16;

  const float scale = 0.044194173824159216f;  // 1/sqrt(512)

  // preload Q A-fragments (full D): A[m=l15][k = kk*32 + quad*8 + jj]
  bf16x8 qf[16];
  {
    const bf16_t* qp = q + ((size_t)(b * 4096 + t0 + l15)) * 512 + quad * 8;
#pragma unroll
    for (int kk = 0; kk < 16; kk++) qf[kk] = *(const bf16x8*)(qp + kk * 32);
  }

  f32x4 oacc[16] = {};  // O[16 x 256] C-layout: oacc[n][r] = O[quad*4+r][half*256+n*16+l15]
  float mrow[4], lrow[4];
#pragma unroll
  for (int r = 0; r < 4; r++) {
    mrow[r] = NEG_BIG;
    lrow[r] = 0.0f;
  }

  const int jcomp = (t0 + 15) >> 5;  // last KV tile with any visible col
  const bf16_t* kbase = k + (size_t)b * 4096 * 512;
  const bf16_t* vbase = vT + ((size_t)b * 512 + half * 256) * 4096;

  for (int j = 0; j <= jcomp; j++) {
    // ---- S[16x32] = Q . K^T (full D)
    f32x4 s0 = {}, s1 = {};
    const bf16_t* krow0 = kbase + (size_t)(j * 32 + l15) * 512 + quad * 8;
    const bf16_t* krow1 = krow0 + 16 * 512;
#pragma unroll
    for (int kk = 0; kk < 16; kk++) {
      const bf16x8 kf0 = *(const bf16x8*)(krow0 + kk * 32);
      const bf16x8 kf1 = *(const bf16x8*)(krow1 + kk * 32);
      s0 = MFMA_BF16(qf[kk], kf0, s0);
      s1 = MFMA_BF16(qf[kk], kf1, s1);
    }

    // ---- scale + causal mask + inf-free online softmax
    float p0[4], p1[4], alpha[4];
#pragma unroll
    for (int r = 0; r < 4; r++) {
      const int trow = t0 + quad * 4 + r;
      const int c0 = j * 32 + l15;
      const float v0 = (c0 <= trow) ? s0[r] * scale : NEG_BIG;
      const float v1 = (c0 + 16 <= trow) ? s1[r] * scale : NEG_BIG;
      float mx = fmaxf(v0, v1);
      mx = fmaxf(mx, __shfl_xor(mx, 1));
      mx = fmaxf(mx, __shfl_xor(mx, 2));
      mx = fmaxf(mx, __shfl_xor(mx, 4));
      mx = fmaxf(mx, __shfl_xor(mx, 8));
      if (mx > 0.5f * NEG_BIG) {
        const float mnew = fmaxf(mrow[r], mx);
        alpha[r] = __expf(mrow[r] - mnew);
        const float e0 = __expf(v0 - mnew);
        const float e1 = __expf(v1 - mnew);
        float rs = e0 + e1;
        rs += __shfl_xor(rs, 1);
        rs += __shfl_xor(rs, 2);
        rs += __shfl_xor(rs, 4);
        rs += __shfl_xor(rs, 8);
        lrow[r] = lrow[r] * alpha[r] + rs;
        mrow[r] = mnew;
        p0[r] = e0;
        p1[r] = e1;
      } else {
        alpha[r] = 1.0f;
        p0[r] = 0.0f;
        p1[r] = 0.0f;
      }
    }
#pragma unroll
    for (int n = 0; n < 16; n++) {
#pragma unroll
      for (int r = 0; r < 4; r++) oacc[n][r] *= alpha[r];
    }

    // ---- P: C-layout -> A-layout via wave-private LDS (m120-verified)
#pragma unroll
    for (int r = 0; r < 4; r++) {
      Ps[(quad * 4 + r) * 32 + l15] = (bf16_t)p0[r];
      Ps[(quad * 4 + r) * 32 + 16 + l15] = (bf16_t)p1[r];
    }
    const bf16x8 pf = *(const bf16x8*)(Ps + l15 * 32 + quad * 8);

    // ---- O += P . V (half-D): vf = V[c=quad*8..+7][d=half*256+n*16+l15]
    const bf16_t* vcol = vbase + (size_t)l15 * 4096 + j * 32 + quad * 8;
#pragma unroll
    for (int n = 0; n < 16; n++) {
      const bf16x8 vf = *(const bf16x8*)(vcol + (size_t)n * 16 * 4096);
      oacc[n] = MFMA_BF16(pf, vf, oacc[n]);
    }
  }

  // ---- epilogue: O / l -> bf16 into this half's 256 columns
#pragma unroll
  for (int r = 0; r < 4; r++) {
    const float inv = 1.0f / lrow[r];
    bf16_t* orow = o + ((size_t)(b * 4096 + t0 + quad * 4 + r)) * 512 + half * 256;
#pragma unroll
    for (int n = 0; n < 16; n++) orow[n * 16 + l15] = (bf16_t)(oacc[n][r] * inv);
  }
}

// ---------------------------------------------------------------------------
extern "C" void kernel_launch(void* const* d_in, const int* in_sizes, int n_in,
                              void* d_out, int out_size, void* d_ws, size_t ws_size,
                              hipStream_t stream) {
  const float* x_f = (const float*)d_in[0];   // [4,4096,512] fp32
  const float* wq_f = (const float*)d_in[1];  // [1536,512]   fp32
  const float* wp_f = (const float*)d_in[2];  // [512,512]    fp32
  float* out = (float*)d_out;                 // [4,4096,512] fp32

  // ws (bf16): xb (16MB, reused as attn output) | wqb | wpb | q | k | vT
  bf16_t* xb = (bf16_t*)d_ws;
  bf16_t* wqb = xb + (size_t)16384 * 512;
  bf16_t* wpb = wqb + (size_t)1536 * 512;
  bf16_t* q = wpb + (size_t)512 * 512;
  bf16_t* kk = q + (size_t)16384 * 512;
  bf16_t* vT = kk + (size_t)16384 * 512;

  // 0) convert fp32 inputs -> bf16
  cvt_kernel<<<(16384 * 512) / 1024, 256, 0, stream>>>(x_f, xb);
  cvt_kernel<<<(1536 * 512) / 1024, 256, 0, stream>>>(wq_f, wqb);
  cvt_kernel<<<(512 * 512) / 1024, 256, 0, stream>>>(wp_f, wpb);

  // 1) qkv = x @ Wqkv^T ; v stored transposed (xb dead afterwards)
  gemm_bt_kernel<0><<<128 * 12, 256, 0, stream>>>(xb, wqb, q, kk, vT, nullptr);
  // 2) causal attention -> xb (2048 single-wave blocks, heavy-first)
  attn_kernel<<<2048, 64, 0, stream>>>(q, kk, vT, xb);
  // 3) y = attn @ Wproj^T -> fp32 d_out
  gemm_bt_kernel<1><<<128 * 4, 256, 0, stream>>>(xb, wpb, nullptr, nullptr, nullptr, out);
}

// Round 8
// 565.576 us; speedup vs baseline: 2.7204x; 1.7648x over previous
//
#include <hip/hip_runtime.h>
#include <hip/hip_bf16.h>
#include <stdint.h>

typedef __bf16 bf16_t;
typedef __bf16 bf16x4 __attribute__((ext_vector_type(4)));
typedef __bf16 bf16x8 __attribute__((ext_vector_type(8)));
typedef float f32x4 __attribute__((ext_vector_type(4)));

static_assert(sizeof(bf16x8) == 16, "bf16x8 must be 16B");

#define MFMA_BF16(a, b, c) __builtin_amdgcn_mfma_f32_16x16x32_bf16((a), (b), (c), 0, 0, 0)

typedef const __attribute__((address_space(1))) void* gas_ptr;
typedef __attribute__((address_space(3))) void* las_ptr;

__device__ __forceinline__ void gload_lds16(const void* g, void* l) {
  __builtin_amdgcn_global_load_lds((gas_ptr)g, (las_ptr)l, 16, 0, 0);
}

#define NEG_BIG (-1.0e30f)

// ---------------------------------------------------------------------------
// fp32 -> bf16 convert
// ---------------------------------------------------------------------------
__global__ __launch_bounds__(256) void cvt_kernel(const float* __restrict__ src,
                                                  bf16_t* __restrict__ dst) {
  const int i = (blockIdx.x * 256 + threadIdx.x) * 4;
  const f32x4 v = *(const f32x4*)(src + i);
  bf16x4 o;
  o[0] = (bf16_t)v[0];
  o[1] = (bf16_t)v[1];
  o[2] = (bf16_t)v[2];
  o[3] = (bf16_t)v[3];
  *(bf16x4*)(dst + i) = o;
}

// ---------------------------------------------------------------------------
// GEMM (m97 structure): D[m][n] = sum_k A[m][k] * Bw[n][k]
// MODE 0: qkv epilogue -> q / k row-major (bf16), v transposed to vT[b][d][t]
// MODE 1: final epilogue -> o_f as FP32 (reference output dtype)
// ---------------------------------------------------------------------------
template <int MODE>
__global__ __launch_bounds__(256, 2) void gemm_bt_kernel(
    const bf16_t* __restrict__ A, const bf16_t* __restrict__ Bw,
    bf16_t* __restrict__ o_q, bf16_t* __restrict__ o_k, bf16_t* __restrict__ o_vT,
    float* __restrict__ o_f) {
  constexpr int K = 512;
  __shared__ bf16_t As[128 * 32];
  __shared__ bf16_t Bs[128 * 32];

  const int tid = threadIdx.x;
  const int lane = tid & 63;
  const int wid = tid >> 6;
  const int quad = lane >> 4;
  const int l15 = lane & 15;
  const int wm = wid >> 1;
  const int wn = wid & 1;

  const int mt = blockIdx.x & 127;
  const int nt = blockIdx.x >> 7;
  const int row0 = mt * 128;
  const int col0 = nt * 128;

  f32x4 acc[4][4] = {};

  for (int kt = 0; kt < K; kt += 32) {
    __syncthreads();
#pragma unroll
    for (int rnd = 0; rnd < 2; rnd++) {
      const int e = (rnd * 256 + tid) * 8;
      const int r = e >> 5;
      const int c = e & 31;
      gload_lds16(A + (size_t)(row0 + r) * K + kt + c, As + e);
      gload_lds16(Bw + (size_t)(col0 + r) * K + kt + c, Bs + e);
    }
    __syncthreads();

    bf16x8 af[4], bfr[4];
#pragma unroll
    for (int i = 0; i < 4; i++)
      af[i] = *(const bf16x8*)(As + (wm * 64 + i * 16 + l15) * 32 + quad * 8);
#pragma unroll
    for (int i = 0; i < 4; i++)
      bfr[i] = *(const bf16x8*)(Bs + (wn * 64 + i * 16 + l15) * 32 + quad * 8);
#pragma unroll
    for (int mi = 0; mi < 4; mi++)
#pragma unroll
      for (int ni = 0; ni < 4; ni++)
        acc[mi][ni] = MFMA_BF16(af[mi], bfr[ni], acc[mi][ni]);
  }

#pragma unroll
  for (int mi = 0; mi < 4; mi++) {
    const int row = row0 + wm * 64 + mi * 16 + quad * 4;
#pragma unroll
    for (int ni = 0; ni < 4; ni++) {
      const int col = col0 + wn * 64 + ni * 16 + l15;
#pragma unroll
      for (int r = 0; r < 4; r++) {
        const int rr = row + r;
        if constexpr (MODE == 0) {
          const bf16_t bv = (bf16_t)acc[mi][ni][r];
          if (col < 512) {
            o_q[(size_t)rr * 512 + col] = bv;
          } else if (col < 1024) {
            o_k[(size_t)rr * 512 + (col - 512)] = bv;
          } else {
            const int bb = rr >> 12;
            const int t = rr & 4095;
            o_vT[((size_t)bb * 512 + (col - 1024)) * 4096 + t] = bv;
          }
        } else {
          o_f[(size_t)rr * 512 + col] = acc[mi][ni][r];
        }
      }
    }
  }
}

// ---------------------------------------------------------------------------
// Flash attention "flash64": block = 4 waves, strip = 64 q-rows (wave w owns
// 16 rows, FULL-D S-phase), output d-halved (oacc 16xf32x4). Grid = 256
// strips x 2 halves = 512 blocks, heavy strips first.
// Per KV-tile (32 cols): Ks[32x512] (32 KB, XOR-swizzled chunks) + Vs[256x32]
// (16 KB, from vT) staged cooperatively via global_load_lds -> 48 KB LDS =>
// 2-3 blocks/CU co-resident (stage/compute overlap across blocks).
// P transpose aliased into Ks (3rd barrier). Inf-free online softmax.
// ---------------------------------------------------------------------------
__global__ __launch_bounds__(256, 2) void attn_kernel(
    const bf16_t* __restrict__ q, const bf16_t* __restrict__ k,
    const bf16_t* __restrict__ vT, bf16_t* __restrict__ o) {
  __shared__ bf16_t Ks[32 * 512];  // 32 KB; P scratch aliased at Ks + wid*512
  __shared__ bf16_t Vs[256 * 32];  // 16 KB (this block's d-half)

  const int tid = threadIdx.x;
  const int lane = tid & 63;
  const int wid = tid >> 6;
  const int quad = lane >> 4;
  const int l15 = lane & 15;

  const int bid = blockIdx.x;       // 0..511
  const int half = bid & 1;         // output-d half
  const int sidx = bid >> 1;        // 0..255
  const int b = sidx & 3;           // batch
  const int s = 63 - (sidx >> 2);   // strip (64 rows); heavy-first
  const int t0 = s * 64 + wid * 16; // this wave's q rows

  const float scale = 0.044194173824159216f;  // 1/sqrt(512)

  // preload Q A-fragments (full D): A[m=l15][k = kk*32 + quad*8 + jj]
  bf16x8 qf[16];
  {
    const bf16_t* qp = q + ((size_t)(b * 4096 + t0 + l15)) * 512 + quad * 8;
#pragma unroll
    for (int kk = 0; kk < 16; kk++) qf[kk] = *(const bf16x8*)(qp + kk * 32);
  }

  f32x4 oacc[16] = {};  // O[16 x 256]: oacc[n][r] = O[quad*4+r][half*256+n*16+l15]
  float mrow[4], lrow[4];
#pragma unroll
  for (int r = 0; r < 4; r++) {
    mrow[r] = NEG_BIG;
    lrow[r] = 0.0f;
  }

  const int jsteps = s * 2 + 2;       // block-uniform KV tiles to stage
  const int jcomp = (t0 + 15) >> 5;   // this wave's last active tile
  const bf16_t* kbase = k + (size_t)b * 4096 * 512;
  const bf16_t* vbase = vT + ((size_t)b * 512 + half * 256) * 4096;

  for (int j = 0; j < jsteps; j++) {
    __syncthreads();  // prev iter's Ks(P)/Vs reads complete
    // stage K tile 32x512 (8 rounds): LDS chunk c of row kr holds global
    // chunk c^(kr&7) -> read side XORs with l15&7 (2-way banks)
#pragma unroll
    for (int rnd = 0; rnd < 8; rnd++) {
      const int ch = rnd * 256 + tid;
      const int kr = ch >> 6;
      const int gc = (ch & 63) ^ (kr & 7);
      gload_lds16(kbase + (size_t)(j * 32 + kr) * 512 + gc * 8, Ks + ch * 8);
    }
    // stage V half-tile 256x32 (4 rounds): Vs[d][c] = vT[half*256+d][j*32+c]
#pragma unroll
    for (int rnd = 0; rnd < 4; rnd++) {
      const int ch = rnd * 256 + tid;
      const int vd = ch >> 2;
      const int vc = (ch & 3) * 8;
      gload_lds16(vbase + (size_t)vd * 4096 + j * 32 + vc, Vs + ch * 8);
    }
    __syncthreads();

    const bool act = (j <= jcomp);
    float p0[4], p1[4];
    if (act) {
      // ---- S[16x32] = Q . K^T (full D), swizzled Ks reads
      f32x4 s0 = {}, s1 = {};
      const int sw = l15 & 7;
#pragma unroll
      for (int kk = 0; kk < 16; kk++) {
        const bf16x8 kf0 =
            *(const bf16x8*)(Ks + l15 * 512 + (((kk * 4 + quad) ^ sw) * 8));
        const bf16x8 kf1 =
            *(const bf16x8*)(Ks + (16 + l15) * 512 + (((kk * 4 + quad) ^ sw) * 8));
        s0 = MFMA_BF16(qf[kk], kf0, s0);
        s1 = MFMA_BF16(qf[kk], kf1, s1);
      }
      // ---- scale + causal mask + inf-free online softmax
      float alpha[4];
#pragma unroll
      for (int r = 0; r < 4; r++) {
        const int trow = t0 + quad * 4 + r;
        const int c0 = j * 32 + l15;
        const float v0 = (c0 <= trow) ? s0[r] * scale : NEG_BIG;
        const float v1 = (c0 + 16 <= trow) ? s1[r] * scale : NEG_BIG;
        float mx = fmaxf(v0, v1);
        mx = fmaxf(mx, __shfl_xor(mx, 1));
        mx = fmaxf(mx, __shfl_xor(mx, 2));
        mx = fmaxf(mx, __shfl_xor(mx, 4));
        mx = fmaxf(mx, __shfl_xor(mx, 8));
        if (mx > 0.5f * NEG_BIG) {
          const float mnew = fmaxf(mrow[r], mx);
          alpha[r] = __expf(mrow[r] - mnew);
          const float e0 = __expf(v0 - mnew);
          const float e1 = __expf(v1 - mnew);
          float rs = e0 + e1;
          rs += __shfl_xor(rs, 1);
          rs += __shfl_xor(rs, 2);
          rs += __shfl_xor(rs, 4);
          rs += __shfl_xor(rs, 8);
          lrow[r] = lrow[r] * alpha[r] + rs;
          mrow[r] = mnew;
          p0[r] = e0;
          p1[r] = e1;
        } else {
          alpha[r] = 1.0f;
          p0[r] = 0.0f;
          p1[r] = 0.0f;
        }
      }
#pragma unroll
      for (int n = 0; n < 16; n++) {
#pragma unroll
        for (int r = 0; r < 4; r++) oacc[n][r] *= alpha[r];
      }
    }

    __syncthreads();  // all waves done reading Ks -> safe to alias P

    if (act) {
      // ---- P: C-layout -> A-layout via wave-private scratch inside Ks
      bf16_t* Pw = Ks + wid * 512;
#pragma unroll
      for (int r = 0; r < 4; r++) {
        Pw[(quad * 4 + r) * 32 + l15] = (bf16_t)p0[r];
        Pw[(quad * 4 + r) * 32 + 16 + l15] = (bf16_t)p1[r];
      }
      const bf16x8 pf = *(const bf16x8*)(Pw + l15 * 32 + quad * 8);
      // ---- O += P . V (d-half): vf = V[c=quad*8..+7][d=n*16+l15]
#pragma unroll
      for (int n = 0; n < 16; n++) {
        const bf16x8 vf = *(const bf16x8*)(Vs + (n * 16 + l15) * 32 + quad * 8);
        oacc[n] = MFMA_BF16(pf, vf, oacc[n]);
      }
    }
  }

  // ---- epilogue: O / l -> bf16 into this half's 256 columns
#pragma unroll
  for (int r = 0; r < 4; r++) {
    const float inv = 1.0f / lrow[r];
    bf16_t* orow = o + ((size_t)(b * 4096 + t0 + quad * 4 + r)) * 512 + half * 256;
#pragma unroll
    for (int n = 0; n < 16; n++) orow[n * 16 + l15] = (bf16_t)(oacc[n][r] * inv);
  }
}

// ---------------------------------------------------------------------------
extern "C" void kernel_launch(void* const* d_in, const int* in_sizes, int n_in,
                              void* d_out, int out_size, void* d_ws, size_t ws_size,
                              hipStream_t stream) {
  const float* x_f = (const float*)d_in[0];   // [4,4096,512] fp32
  const float* wq_f = (const float*)d_in[1];  // [1536,512]   fp32
  const float* wp_f = (const float*)d_in[2];  // [512,512]    fp32
  float* out = (float*)d_out;                 // [4,4096,512] fp32

  // ws (bf16): xb (16MB, reused as attn output) | wqb | wpb | q | k | vT
  bf16_t* xb = (bf16_t*)d_ws;
  bf16_t* wqb = xb + (size_t)16384 * 512;
  bf16_t* wpb = wqb + (size_t)1536 * 512;
  bf16_t* q = wpb + (size_t)512 * 512;
  bf16_t* kk = q + (size_t)16384 * 512;
  bf16_t* vT = kk + (size_t)16384 * 512;

  // 0) convert fp32 inputs -> bf16
  cvt_kernel<<<(16384 * 512) / 1024, 256, 0, stream>>>(x_f, xb);
  cvt_kernel<<<(1536 * 512) / 1024, 256, 0, stream>>>(wq_f, wqb);
  cvt_kernel<<<(512 * 512) / 1024, 256, 0, stream>>>(wp_f, wpb);

  // 1) qkv = x @ Wqkv^T ; v stored transposed (xb dead afterwards)
  gemm_bt_kernel<0><<<128 * 12, 256, 0, stream>>>(xb, wqb, q, kk, vT, nullptr);
  // 2) causal attention -> xb (512 blocks: 256 strips x 2 d-halves)
  attn_kernel<<<512, 256, 0, stream>>>(q, kk, vT, xb);
  // 3) y = attn @ Wproj^T -> fp32 d_out
  gemm_bt_kernel<1><<<128 * 4, 256, 0, stream>>>(xb, wpb, nullptr, nullptr, nullptr, out);
}